// Round 1
// baseline (109.784 us; speedup 1.0000x reference)
//
#include <hip/hip_runtime.h>

#define NB 8
#define LEN 256
#define DIM 768
#define NC 3976
// output layout (floats): fofe_codes [8][3976][5][768] = 122142720,
// cands_pos [8][3976][2] = 63616, padded [8][3976] = 31808
#define OFF_POS 122142720
#define OFF_PAD (122142720 + 63616)

constexpr float ALPHA_F = 0.9f;
constexpr float A32 = 0.03433683820292512f;  // 0.9^32

// Prefix/suffix geometric scan: P[l] = x[l] + a*P[l-1], S[l] = x[l] + a*S[l+1].
// block = 256 threads: 32 d-lanes x 8 l-chunks (32 elems each).
// grid = (DIM/32 = 24, NB, 2 directions)
__global__ __launch_bounds__(256) void scan_kernel(const float* __restrict__ x,
                                                   float* __restrict__ P,
                                                   float* __restrict__ S) {
    const int dl = threadIdx.x & 31;
    const int chunk = threadIdx.x >> 5;
    const int d = blockIdx.x * 32 + dl;
    const int b = blockIdx.y;
    const int dir = blockIdx.z;
    const float* __restrict__ xb = x + (size_t)b * LEN * DIM;
    float* __restrict__ ob = (dir ? S : P) + (size_t)b * LEN * DIM;

    float vals[32];
    float acc = 0.f;
#pragma unroll
    for (int t = 0; t < 32; ++t) {
        const int lm = chunk * 32 + t;
        const int l = dir ? (LEN - 1 - lm) : lm;
        acc = fmaf(ALPHA_F, acc, xb[l * DIM + d]);
        vals[t] = acc;
    }

    __shared__ float ends[8][32];
    ends[chunk][dl] = acc;
    __syncthreads();

    // carry into this chunk: C_k = end[k-1] + a^32 * C_{k-1}
    float carry = 0.f;
    for (int k = 0; k < chunk; ++k)
        carry = fmaf(A32, carry, ends[k][dl]);

    float w = ALPHA_F;
#pragma unroll
    for (int t = 0; t < 32; ++t) {
        const int lm = chunk * 32 + t;
        const int l = dir ? (LEN - 1 - lm) : lm;
        ob[l * DIM + d] = fmaf(w, carry, vals[t]);
        w *= ALPHA_F;
    }
}

// One 192-thread block per (candidate, batch). Each thread handles one float4
// of the 768-dim embedding for all 5 context codes.
__global__ __launch_bounds__(192) void out_kernel(const float* __restrict__ P,
                                                  const float* __restrict__ S,
                                                  const int* __restrict__ mask,
                                                  float* __restrict__ out) {
    const int c = blockIdx.x;
    const int b = blockIdx.y;
    const int t = threadIdx.x;

    // decode candidate c -> (start i, span s); starts 0..240 have 16 spans,
    // 241..255 have 15..1 spans (start-major, span ascending)
    int i, s;
    if (c < 3856) {
        i = c >> 4;
        s = c & 15;
    } else {
        int r = c - 3856;
        int u = 0, off = 0;
        while (off + (15 - u) <= r) { off += 15 - u; ++u; }
        i = 241 + u;
        s = r - off;
    }
    const int e = i + s;

    float w = ALPHA_F;  // alpha^(s+1)
    for (int q = 0; q < s; ++q) w *= ALPHA_F;

    const float4 z4 = make_float4(0.f, 0.f, 0.f, 0.f);
    const float4* __restrict__ Pb = (const float4*)(P + (size_t)b * LEN * DIM);
    const float4* __restrict__ Sb = (const float4*)(S + (size_t)b * LEN * DIM);

    const float4 pm1 = (i > 0) ? Pb[(i - 1) * 192 + t] : z4;       // left excl
    const float4 pe = Pb[e * 192 + t];                             // left incl
    const float4 si = Sb[i * 192 + t];                             // right incl
    const float4 se1 = (e < LEN - 1) ? Sb[(e + 1) * 192 + t] : z4; // right excl
    float4 cand;
    cand.x = fmaf(-w, pm1.x, pe.x);
    cand.y = fmaf(-w, pm1.y, pe.y);
    cand.z = fmaf(-w, pm1.z, pe.z);
    cand.w = fmaf(-w, pm1.w, pe.w);

    float4* __restrict__ o = (float4*)out + (size_t)(b * NC + c) * 960;
    o[0 * 192 + t] = pm1;  // [left_excl, left_incl, cand, right_incl, right_excl]
    o[1 * 192 + t] = pe;
    o[2 * 192 + t] = cand;
    o[3 * 192 + t] = si;
    o[4 * 192 + t] = se1;

    if (t < 64) {  // wave 0: cands_pos + padded_cands
        int m = 0;
        if (t < 16 && t <= s) m = mask[b * LEN + i + t];
        unsigned long long ball = __ballot(m != 0);
        if (t == 0) {
            out[OFF_POS + (size_t)(b * NC + c) * 2] = (float)i;
            out[OFF_POS + (size_t)(b * NC + c) * 2 + 1] = (float)e;
            out[OFF_PAD + (size_t)(b * NC + c)] = ball ? 1.f : 0.f;
        }
    }
}

extern "C" void kernel_launch(void* const* d_in, const int* in_sizes, int n_in,
                              void* d_out, int out_size, void* d_ws, size_t ws_size,
                              hipStream_t stream) {
    const float* x = (const float*)d_in[0];
    const int* mask = (const int*)d_in[1];
    float* out = (float*)d_out;
    float* P = (float*)d_ws;                  // [8][256][768] fp32
    float* S = P + (size_t)NB * LEN * DIM;    // [8][256][768] fp32  (12.6 MB total)

    scan_kernel<<<dim3(DIM / 32, NB, 2), 256, 0, stream>>>(x, P, S);
    out_kernel<<<dim3(NC, NB), 192, 0, stream>>>(P, S, mask, out);
}